// Round 11
// baseline (456.606 us; speedup 1.0000x reference)
//
#include <hip/hip_runtime.h>
#include <hip/hip_fp16.h>

// Wavelet lifting net, MI355X — TWO fused launches, 512-thread blocks.
// r11 = r8 (verified fused kernel, 256t, absmax 0.03125) + ONE change:
//   512 threads/block (8 waves, standard power of two) so phase-A's 289
//   tiles run in a single lane-parallel pass. r8's 256t ran 33 extra tiles
//   as a serialized second pass (~9us/launch of SIMD under-subscription).
//   NOTE: 320-thread (5-wave) blocks container-failed twice (r9/r10) —
//   non-power-of-2 block sizes are banned for the rest of this session.
// Occupancy: 768 blocks = 3 blocks/CU = 24 waves/CU; VGPR 68 x 6 waves/SIMD
// = 408 < 512 pool -> launch_bounds(512,6) safe. LDS 22.7KB x 3 = 68KB.
// Phase B / interior write: verified tid<256 4x4 body (4 waves exit early;
// per-CU subscription unaffected).
//  Launch A (FUSE=0): Hb' = YUVodd - p(YUVeven)  [68x68 -> LDS, interior->Hw]
//                     L'  = YUVeven + u(Hb')     [64x64 -> Lw]
//  Launch B (FUSE=1): q1  = oddcols - pT(evencols) [68x68 -> LDS, interior->out]
//                     q0  = evencols + uT(q1)      [64x64 -> out]
// In-place LDS epilogue race-free (each tile owns its io slots; barriered).
// OOB outputs stored 0 (matches zero-fill staging semantics).
// Dead ends: coop launch (r2/3), small-tile occupancy (r1/r6), io hoist
// (r4 write-amp), weight ping-pong (r5), 320t blocks (r9/r10),
// batched reg staging (r9).

#define P1 (24*256*512)

__device__ __forceinline__ __half2 oddpair(__half2 a, __half2 b) {
  unsigned ua = __builtin_bit_cast(unsigned, a), ub = __builtin_bit_cast(unsigned, b);
  unsigned r = __builtin_amdgcn_alignbit(ub, ua, 16);
  return __builtin_bit_cast(__half2, r);
}

__device__ __forceinline__ __half2 relu2(__half2 s) {
  unsigned u = __builtin_bit_cast(unsigned, s), r;
  asm("v_pk_max_f16 %0, %1, 0" : "=v"(r) : "v"(u));
  return __builtin_bit_cast(__half2, r);
}

__device__ __forceinline__ void load20(__half2 (&wv)[20], const __half2* src) {
  const float4* wq = (const float4*)src;
#pragma unroll
  for (int q = 0; q < 5; ++q) {
    float4 f = wq[q];
    wv[4*q+0] = __builtin_bit_cast(__half2, f.x);
    wv[4*q+1] = __builtin_bit_cast(__half2, f.y);
    wv[4*q+2] = __builtin_bit_cast(__half2, f.z);
    wv[4*q+3] = __builtin_bit_cast(__half2, f.w);
  }
}

// one channel's conv1(relu)+conv2 accumulation — verified body (r0..r8).
__device__ __forceinline__ void channel_pass(
    const __half2 (&wv)[20],
    const __half2 (&E)[8][4], const __half2 (&O)[8][3],
    const bool (&rowok)[6], const bool edgex, const __half2 (&mE)[3],
    __half2 (&ACC2)[4][2], const __half2 negb)
{
  __half2 bias[6];
#pragma unroll
  for (int k = 0; k < 6; ++k) bias[k] = rowok[k] ? wv[9] : negb;

#pragma unroll
  for (int kk = 0; kk < 6; ++kk) {
    __half2 HE[3];
#pragma unroll
    for (int p = 0; p < 3; ++p) {
      __half2 hs = bias[kk];
#pragma unroll
      for (int dy = 0; dy < 3; ++dy) {
        hs = __hfma2(wv[dy*3+0], E[kk+dy][p],   hs);
        hs = __hfma2(wv[dy*3+1], O[kk+dy][p],   hs);
        hs = __hfma2(wv[dy*3+2], E[kk+dy][p+1], hs);
      }
      HE[p] = relu2(hs);
    }
    if (edgex) {
      HE[0] = __hmul2(HE[0], mE[0]);
      HE[1] = __hmul2(HE[1], mE[1]);
      HE[2] = __hmul2(HE[2], mE[2]);
    }
    __half2 HO0 = oddpair(HE[0], HE[1]);
    __half2 HO1 = oddpair(HE[1], HE[2]);
#pragma unroll
    for (int dy = 0; dy < 3; ++dy) {
      const int r = kk - dy;
      if (r >= 0 && r < 4) {
#pragma unroll
        for (int cp = 0; cp < 2; ++cp) {
          __half2 a = ACC2[r][cp];
          a = __hfma2(wv[10+dy*3+0], HE[cp],           a);
          a = __hfma2(wv[10+dy*3+1], (cp ? HO1 : HO0), a);
          a = __hfma2(wv[10+dy*3+2], HE[cp+1],         a);
          ACC2[r][cp] = a;
        }
      }
    }
  }
}

template<int FUSE>
__global__ __launch_bounds__(512, 6) void k_pair(
    const float* __restrict__ xp, float* __restrict__ ws, float* __restrict__ outp,
    const float* __restrict__ Wp1, const float* __restrict__ bp1,
    const float* __restrict__ Wp2, const float* __restrict__ bp2,
    const float* __restrict__ Wu1, const float* __restrict__ bu1,
    const float* __restrict__ Wu2, const float* __restrict__ bu2)
{
  constexpr int IW = FUSE ? 256 : 512;           // logical col count
  constexpr unsigned IWu = (unsigned)IW;

  __shared__ __align__(16) __half2 sWp[16*20];
  __shared__ __align__(16) __half2 sWu[16*20];
  __shared__ __align__(16) __half  sEven[72*72]; // origin (y0-4, x0-4)
  __shared__ __align__(16) __half  sOdd [68*72]; // origin (y0-2, x0-4); becomes Hb'/q1

  const int z = blockIdx.z;
  const int n     = FUSE ? (z % 24) : z;
  const int which = FUSE ? (z / 24) : 0;
  const int c_ = n >> 3, b_ = n & 7;
  const int x0 = blockIdx.x * 64, y0 = blockIdx.y * 64;
  const int tid = threadIdx.x;
  float* Lw = ws;
  float* Hw = ws + P1;

  // ---- both weight sets -> LDS (transposed 3x3 if FUSE) ----
  for (int i = tid; i < 640; i += 512) {
    int st = (i >= 320) ? 1 : 0, j2 = i - 320*st;
    int cc = j2 / 20, j = j2 - cc*20;
    const float* W1 = st ? Wu1 : Wp1;
    const float* B1 = st ? bu1 : bp1;
    const float* W2 = st ? Wu2 : Wp2;
    float v = 0.f;
    if (j < 9)       { int jt = FUSE ? ((j%3)*3 + j/3) : j; v = W1[cc*9 + jt]; }
    else if (j == 9) v = B1[cc];
    else if (j < 19) { int k = j - 10; int jt = FUSE ? ((k%3)*3 + k/3) : k; v = W2[cc*9 + jt]; }
    __half h = __float2half(v);
    (st ? sWu : sWp)[j2] = __halves2half2(h, h);
  }

  float m0 = 0.f, m1 = 0.f, m2 = 0.f;
  if (FUSE == 0) {
    m0 = (c_==0) ? 0.299f : ((c_==1) ? -0.147f :  0.615f);
    m1 = (c_==0) ? 0.587f : ((c_==1) ? -0.289f : -0.515f);
    m2 = (c_==0) ? 0.114f : ((c_==1) ?  0.436f : -0.100f);
  }
  const float* srcq = FUSE ? ((which ? Hw : Lw) + (long)n*131072) : nullptr;

  // ---- stage sEven: 72 rows x 18 aligned float4 groups ----
  for (int i = tid; i < 72*18; i += 512) {
    int ly = i / 18, g = i - ly*18;
    int gy = y0 + ly - 4, gx = x0 + 4*g - 4;
    float4 f = make_float4(0.f, 0.f, 0.f, 0.f);
    if ((unsigned)gy < 256u && (unsigned)gx < IWu) {
      if (FUSE == 0) {
        const float* xb = xp + (long)b_*786432 + (2*gy)*512 + gx;
        float4 rr = *(const float4*)&xb[0];
        float4 gg = *(const float4*)&xb[262144];
        float4 bb = *(const float4*)&xb[524288];
        f.x = m0*rr.x + m1*gg.x + m2*bb.x;
        f.y = m0*rr.y + m1*gg.y + m2*bb.y;
        f.z = m0*rr.z + m1*gg.z + m2*bb.z;
        f.w = m0*rr.w + m1*gg.w + m2*bb.w;
      } else {
        const float* s = srcq + gy*512 + 2*gx;
        float4 a = *(const float4*)&s[0];
        float4 b = *(const float4*)&s[4];
        f = make_float4(a.x, a.z, b.x, b.z);        // even cols
      }
    }
    __half2* d = (__half2*)&sEven[ly*72 + 4*g];
    d[0] = __halves2half2(__float2half(f.x), __float2half(f.y));
    d[1] = __halves2half2(__float2half(f.z), __float2half(f.w));
  }
  // ---- stage sOdd: 68 rows x 18 groups ----
  for (int i = tid; i < 68*18; i += 512) {
    int ly = i / 18, g = i - ly*18;
    int gy = y0 + ly - 2, gx = x0 + 4*g - 4;
    float4 f = make_float4(0.f, 0.f, 0.f, 0.f);
    if ((unsigned)gy < 256u && (unsigned)gx < IWu) {
      if (FUSE == 0) {
        const float* xb = xp + (long)b_*786432 + (2*gy + 1)*512 + gx;
        float4 rr = *(const float4*)&xb[0];
        float4 gg = *(const float4*)&xb[262144];
        float4 bb = *(const float4*)&xb[524288];
        f.x = m0*rr.x + m1*gg.x + m2*bb.x;
        f.y = m0*rr.y + m1*gg.y + m2*bb.y;
        f.z = m0*rr.z + m1*gg.z + m2*bb.z;
        f.w = m0*rr.w + m1*gg.w + m2*bb.w;
      } else {
        const float* s = srcq + gy*512 + 2*gx;
        float4 a = *(const float4*)&s[0];
        float4 b = *(const float4*)&s[4];
        f = make_float4(a.y, a.w, b.y, b.w);        // odd cols
      }
    }
    __half2* d = (__half2*)&sOdd[ly*72 + 4*g];
    d[0] = __halves2half2(__float2half(f.x), __float2half(f.y));
    d[1] = __halves2half2(__float2half(f.z), __float2half(f.w));
  }
  __syncthreads();

  const __half2 zero2 = __builtin_bit_cast(__half2, 0u);
  const __half2 negb  = __halves2half2(__float2half(-60000.f), __float2half(-60000.f));
  const float b2p = bp2[0];

  // ---- phase A: predict-step on 68x68 region, 289 tiles, ONE pass ----
  if (tid < 289) {
    const int tyA = tid / 17, txA = tid - tyA*17;
    const int oyA = y0 - 2 + 4*tyA, oxA = x0 - 2 + 4*txA;
    __half2 E[8][4], O[8][3];
#pragma unroll
    for (int r = 0; r < 8; ++r) {
      const __half2* row = (const __half2*)&sEven[(4*tyA + r)*72 + 4*txA];
      E[r][0] = row[0]; E[r][1] = row[1]; E[r][2] = row[2]; E[r][3] = row[3];
      O[r][0] = oddpair(E[r][0], E[r][1]);
      O[r][1] = oddpair(E[r][1], E[r][2]);
      O[r][2] = oddpair(E[r][2], E[r][3]);
    }
    bool rowokA[6];
#pragma unroll
    for (int k = 0; k < 6; ++k) rowokA[k] = ((unsigned)(oyA - 1 + k) < 256u);
    const bool edgexT = (oxA <= 0) || (oxA >= IW - 4);
    __half2 mEA[3];
#pragma unroll
    for (int p = 0; p < 3; ++p) mEA[p] = zero2;
    if (edgexT) {
#pragma unroll
      for (int p = 0; p < 3; ++p) {
        float a = ((unsigned)(oxA - 1 + 2*p) < IWu) ? 1.f : 0.f;
        float b = ((unsigned)(oxA     + 2*p) < IWu) ? 1.f : 0.f;
        mEA[p] = __halves2half2(__float2half(a), __float2half(b));
      }
    }
    float   ACCF[4][4] = {{0,0,0,0},{0,0,0,0},{0,0,0,0},{0,0,0,0}};
    __half2 ACC2[4][2] = {{zero2,zero2},{zero2,zero2},{zero2,zero2},{zero2,zero2}};
#pragma unroll 1
    for (int c = 0; c < 16; ++c) {
      __half2 wv[20];
      load20(wv, &sWp[c*20]);
      channel_pass(wv, E, O, rowokA, edgexT, mEA, ACC2, negb);
      if ((c & 3) == 3) {
#pragma unroll
        for (int r = 0; r < 4; ++r)
#pragma unroll
          for (int cp = 0; cp < 2; ++cp) {
            ACCF[r][2*cp]   += __low2float(ACC2[r][cp]);
            ACCF[r][2*cp+1] += __high2float(ACC2[r][cp]);
            ACC2[r][cp] = zero2;
          }
      }
    }
    // epilogue: out = io - (acc + b2p), in-place over own io slots; OOB -> 0
#pragma unroll
    for (int r = 0; r < 4; ++r) {
      const int gy = oyA + r;
      const bool gyok = (unsigned)gy < 256u;
      __half2* iop = (__half2*)&sOdd[(4*tyA + r)*72 + 4*txA + 2];
      __half2 i01 = iop[0], i23 = iop[1];
      float o0 = __low2float (i01) - (ACCF[r][0] + b2p);
      float o1 = __high2float(i01) - (ACCF[r][1] + b2p);
      float o2 = __low2float (i23) - (ACCF[r][2] + b2p);
      float o3 = __high2float(i23) - (ACCF[r][3] + b2p);
      __half h0  = (gyok && (unsigned)(oxA+0) < IWu) ? __float2half(o0) : __half(0);
      __half h1  = (gyok && (unsigned)(oxA+1) < IWu) ? __float2half(o1) : __half(0);
      __half h2_ = (gyok && (unsigned)(oxA+2) < IWu) ? __float2half(o2) : __half(0);
      __half h3  = (gyok && (unsigned)(oxA+3) < IWu) ? __float2half(o3) : __half(0);
      iop[0] = __halves2half2(h0, h1);
      iop[1] = __halves2half2(h2_, h3);
    }
  }
  __syncthreads();

  // ---- interior f32 write of phase-A result + phase B (tid < 256) ----
  if (tid < 256) {
    const int tx = tid & 15, ty = tid >> 4;
    const int oy = y0 + 4*ty, ox = x0 + 4*tx;
    {
      float* pAdst = FUSE ? (outp + (long)(b_*12 + (which?9:3) + c_)*65536)
                          : (Hw + (long)n*131072);
#pragma unroll
      for (int r = 0; r < 4; ++r) {
        const __half2* q = (const __half2*)&sOdd[(4*ty + 2 + r)*72 + 4*tx + 4];
        __half2 a = q[0], b = q[1];
        float4 v = make_float4(__low2float(a), __high2float(a),
                               __low2float(b), __high2float(b));
        *(float4*)&pAdst[(oy + r)*IW + ox] = v;
      }
    }

    // phase B: update-step on interior 64x64
    __half2 E[8][4], O[8][3];
#pragma unroll
    for (int r = 0; r < 8; ++r) {
      const __half2* row = (const __half2*)&sOdd[(4*ty + r)*72 + 4*tx + 2];
      E[r][0] = row[0]; E[r][1] = row[1]; E[r][2] = row[2]; E[r][3] = row[3];
      O[r][0] = oddpair(E[r][0], E[r][1]);
      O[r][1] = oddpair(E[r][1], E[r][2]);
      O[r][2] = oddpair(E[r][2], E[r][3]);
    }
    bool rowok[6];
#pragma unroll
    for (int k = 0; k < 6; ++k) rowok[k] = ((unsigned)(oy - 1 + k) < 256u);
    const bool edgex = (x0 == 0) || (x0 + 64 == IW);
    __half2 mE[3];
#pragma unroll
    for (int p = 0; p < 3; ++p) mE[p] = zero2;
    if (edgex) {
#pragma unroll
      for (int p = 0; p < 3; ++p) {
        float a = ((unsigned)(ox - 1 + 2*p) < IWu) ? 1.f : 0.f;
        float b = ((unsigned)(ox     + 2*p) < IWu) ? 1.f : 0.f;
        mE[p] = __halves2half2(__float2half(a), __float2half(b));
      }
    }
    float   ACCF[4][4] = {{0,0,0,0},{0,0,0,0},{0,0,0,0},{0,0,0,0}};
    __half2 ACC2[4][2] = {{zero2,zero2},{zero2,zero2},{zero2,zero2},{zero2,zero2}};
#pragma unroll 1
    for (int c = 0; c < 16; ++c) {
      __half2 wv[20];
      load20(wv, &sWu[c*20]);
      channel_pass(wv, E, O, rowok, edgex, mE, ACC2, negb);
      if ((c & 3) == 3) {
#pragma unroll
        for (int r = 0; r < 4; ++r)
#pragma unroll
          for (int cp = 0; cp < 2; ++cp) {
            ACCF[r][2*cp]   += __low2float(ACC2[r][cp]);
            ACCF[r][2*cp+1] += __high2float(ACC2[r][cp]);
            ACC2[r][cp] = zero2;
          }
      }
    }
    // epilogue: out = io + (acc + b2u); io = sEven interior
    const float b2u = bu2[0];
    float* dst = FUSE ? (outp + (long)(b_*12 + (which?6:0) + c_)*65536)
                      : (Lw + (long)n*131072);
#pragma unroll
    for (int r = 0; r < 4; ++r) {
      const __half2* iop = (const __half2*)&sEven[(4*ty + 4 + r)*72 + 4*tx + 4];
      __half2 a = iop[0], b = iop[1];
      float4 v;
      v.x = __low2float (a) + (ACCF[r][0] + b2u);
      v.y = __high2float(a) + (ACCF[r][1] + b2u);
      v.z = __low2float (b) + (ACCF[r][2] + b2u);
      v.w = __high2float(b) + (ACCF[r][3] + b2u);
      *(float4*)&dst[(oy + r)*IW + ox] = v;
    }
  }
}

extern "C" void kernel_launch(void* const* d_in, const int* in_sizes, int n_in,
                              void* d_out, int out_size, void* d_ws, size_t ws_size,
                              hipStream_t stream) {
  const float* x   = (const float*)d_in[0];
  const float* Wp1 = (const float*)d_in[1];
  const float* bp1 = (const float*)d_in[2];
  const float* Wp2 = (const float*)d_in[3];
  const float* bp2 = (const float*)d_in[4];
  const float* Wu1 = (const float*)d_in[5];
  const float* bu1 = (const float*)d_in[6];
  const float* Wu2 = (const float*)d_in[7];
  const float* bu2 = (const float*)d_in[8];
  float* out = (float*)d_out;
  float* ws  = (float*)d_ws;

  // Launch A: stage-1 lift (rows): Hb' -> Hw, L' -> Lw
  k_pair<0><<<dim3(8,4,24), 512, 0, stream>>>(x, ws, out,
      Wp1, bp1, Wp2, bp2, Wu1, bu1, Wu2, bu2);
  // Launch B: stage-2 lift (cols, T wts): q1/q3 + q0/q2 -> out
  k_pair<1><<<dim3(4,4,48), 512, 0, stream>>>(x, ws, out,
      Wp1, bp1, Wp2, bp2, Wu1, bu1, Wu2, bu2);
}

// Round 12
// 272.010 us; speedup vs baseline: 1.6786x; 1.6786x over previous
//
#include <hip/hip_runtime.h>
#include <hip/hip_fp16.h>

// Wavelet lifting net, MI355X — TWO fused launches, 512-thread blocks.
// r12 = r11 with ONE fix: __launch_bounds__(512,4) instead of (512,6).
//   r11's (512,6) capped VGPR at 512/6=85 -> compiler spilled the channel
//   loop to scratch (VGPR 40, WRITE 208MB of spill traffic, 200us/launch).
//   (512,4) caps at 128: fits the ~68-84 the body needs, zero spill,
//   2 blocks/CU = 16 waves/CU (more latency hiding than r8's 12).
// Phase-A's 289 tiles run in ONE lane-parallel pass (512 threads);
// r8's 256t double-pass (~9us/launch serialization) eliminated.
//  Launch A (FUSE=0): Hb' = YUVodd - p(YUVeven)  [68x68 -> LDS, interior->Hw]
//                     L'  = YUVeven + u(Hb')     [64x64 -> Lw]
//  Launch B (FUSE=1): q1  = oddcols - pT(evencols) [68x68 -> LDS, interior->out]
//                     q0  = evencols + uT(q1)      [64x64 -> out]
// In-place LDS epilogue race-free (each tile owns its io slots; barriered).
// OOB outputs stored 0 (matches zero-fill staging semantics).
// Dead ends: coop launch (r2/3), small-tile occupancy (r1/r6), io hoist
// (r4 write-amp), weight ping-pong (r5), 320t blocks (r9/r10 container
// fails), batched reg staging (r9), launch_bounds VGPR-cap spill (r11).

#define P1 (24*256*512)

__device__ __forceinline__ __half2 oddpair(__half2 a, __half2 b) {
  unsigned ua = __builtin_bit_cast(unsigned, a), ub = __builtin_bit_cast(unsigned, b);
  unsigned r = __builtin_amdgcn_alignbit(ub, ua, 16);
  return __builtin_bit_cast(__half2, r);
}

__device__ __forceinline__ __half2 relu2(__half2 s) {
  unsigned u = __builtin_bit_cast(unsigned, s), r;
  asm("v_pk_max_f16 %0, %1, 0" : "=v"(r) : "v"(u));
  return __builtin_bit_cast(__half2, r);
}

__device__ __forceinline__ void load20(__half2 (&wv)[20], const __half2* src) {
  const float4* wq = (const float4*)src;
#pragma unroll
  for (int q = 0; q < 5; ++q) {
    float4 f = wq[q];
    wv[4*q+0] = __builtin_bit_cast(__half2, f.x);
    wv[4*q+1] = __builtin_bit_cast(__half2, f.y);
    wv[4*q+2] = __builtin_bit_cast(__half2, f.z);
    wv[4*q+3] = __builtin_bit_cast(__half2, f.w);
  }
}

// one channel's conv1(relu)+conv2 accumulation — verified body (r0..r8).
__device__ __forceinline__ void channel_pass(
    const __half2 (&wv)[20],
    const __half2 (&E)[8][4], const __half2 (&O)[8][3],
    const bool (&rowok)[6], const bool edgex, const __half2 (&mE)[3],
    __half2 (&ACC2)[4][2], const __half2 negb)
{
  __half2 bias[6];
#pragma unroll
  for (int k = 0; k < 6; ++k) bias[k] = rowok[k] ? wv[9] : negb;

#pragma unroll
  for (int kk = 0; kk < 6; ++kk) {
    __half2 HE[3];
#pragma unroll
    for (int p = 0; p < 3; ++p) {
      __half2 hs = bias[kk];
#pragma unroll
      for (int dy = 0; dy < 3; ++dy) {
        hs = __hfma2(wv[dy*3+0], E[kk+dy][p],   hs);
        hs = __hfma2(wv[dy*3+1], O[kk+dy][p],   hs);
        hs = __hfma2(wv[dy*3+2], E[kk+dy][p+1], hs);
      }
      HE[p] = relu2(hs);
    }
    if (edgex) {
      HE[0] = __hmul2(HE[0], mE[0]);
      HE[1] = __hmul2(HE[1], mE[1]);
      HE[2] = __hmul2(HE[2], mE[2]);
    }
    __half2 HO0 = oddpair(HE[0], HE[1]);
    __half2 HO1 = oddpair(HE[1], HE[2]);
#pragma unroll
    for (int dy = 0; dy < 3; ++dy) {
      const int r = kk - dy;
      if (r >= 0 && r < 4) {
#pragma unroll
        for (int cp = 0; cp < 2; ++cp) {
          __half2 a = ACC2[r][cp];
          a = __hfma2(wv[10+dy*3+0], HE[cp],           a);
          a = __hfma2(wv[10+dy*3+1], (cp ? HO1 : HO0), a);
          a = __hfma2(wv[10+dy*3+2], HE[cp+1],         a);
          ACC2[r][cp] = a;
        }
      }
    }
  }
}

template<int FUSE>
__global__ __launch_bounds__(512, 4) void k_pair(
    const float* __restrict__ xp, float* __restrict__ ws, float* __restrict__ outp,
    const float* __restrict__ Wp1, const float* __restrict__ bp1,
    const float* __restrict__ Wp2, const float* __restrict__ bp2,
    const float* __restrict__ Wu1, const float* __restrict__ bu1,
    const float* __restrict__ Wu2, const float* __restrict__ bu2)
{
  constexpr int IW = FUSE ? 256 : 512;           // logical col count
  constexpr unsigned IWu = (unsigned)IW;

  __shared__ __align__(16) __half2 sWp[16*20];
  __shared__ __align__(16) __half2 sWu[16*20];
  __shared__ __align__(16) __half  sEven[72*72]; // origin (y0-4, x0-4)
  __shared__ __align__(16) __half  sOdd [68*72]; // origin (y0-2, x0-4); becomes Hb'/q1

  const int z = blockIdx.z;
  const int n     = FUSE ? (z % 24) : z;
  const int which = FUSE ? (z / 24) : 0;
  const int c_ = n >> 3, b_ = n & 7;
  const int x0 = blockIdx.x * 64, y0 = blockIdx.y * 64;
  const int tid = threadIdx.x;
  float* Lw = ws;
  float* Hw = ws + P1;

  // ---- both weight sets -> LDS (transposed 3x3 if FUSE) ----
  for (int i = tid; i < 640; i += 512) {
    int st = (i >= 320) ? 1 : 0, j2 = i - 320*st;
    int cc = j2 / 20, j = j2 - cc*20;
    const float* W1 = st ? Wu1 : Wp1;
    const float* B1 = st ? bu1 : bp1;
    const float* W2 = st ? Wu2 : Wp2;
    float v = 0.f;
    if (j < 9)       { int jt = FUSE ? ((j%3)*3 + j/3) : j; v = W1[cc*9 + jt]; }
    else if (j == 9) v = B1[cc];
    else if (j < 19) { int k = j - 10; int jt = FUSE ? ((k%3)*3 + k/3) : k; v = W2[cc*9 + jt]; }
    __half h = __float2half(v);
    (st ? sWu : sWp)[j2] = __halves2half2(h, h);
  }

  float m0 = 0.f, m1 = 0.f, m2 = 0.f;
  if (FUSE == 0) {
    m0 = (c_==0) ? 0.299f : ((c_==1) ? -0.147f :  0.615f);
    m1 = (c_==0) ? 0.587f : ((c_==1) ? -0.289f : -0.515f);
    m2 = (c_==0) ? 0.114f : ((c_==1) ?  0.436f : -0.100f);
  }
  const float* srcq = FUSE ? ((which ? Hw : Lw) + (long)n*131072) : nullptr;

  // ---- stage sEven: 72 rows x 18 aligned float4 groups ----
  for (int i = tid; i < 72*18; i += 512) {
    int ly = i / 18, g = i - ly*18;
    int gy = y0 + ly - 4, gx = x0 + 4*g - 4;
    float4 f = make_float4(0.f, 0.f, 0.f, 0.f);
    if ((unsigned)gy < 256u && (unsigned)gx < IWu) {
      if (FUSE == 0) {
        const float* xb = xp + (long)b_*786432 + (2*gy)*512 + gx;
        float4 rr = *(const float4*)&xb[0];
        float4 gg = *(const float4*)&xb[262144];
        float4 bb = *(const float4*)&xb[524288];
        f.x = m0*rr.x + m1*gg.x + m2*bb.x;
        f.y = m0*rr.y + m1*gg.y + m2*bb.y;
        f.z = m0*rr.z + m1*gg.z + m2*bb.z;
        f.w = m0*rr.w + m1*gg.w + m2*bb.w;
      } else {
        const float* s = srcq + gy*512 + 2*gx;
        float4 a = *(const float4*)&s[0];
        float4 b = *(const float4*)&s[4];
        f = make_float4(a.x, a.z, b.x, b.z);        // even cols
      }
    }
    __half2* d = (__half2*)&sEven[ly*72 + 4*g];
    d[0] = __halves2half2(__float2half(f.x), __float2half(f.y));
    d[1] = __halves2half2(__float2half(f.z), __float2half(f.w));
  }
  // ---- stage sOdd: 68 rows x 18 groups ----
  for (int i = tid; i < 68*18; i += 512) {
    int ly = i / 18, g = i - ly*18;
    int gy = y0 + ly - 2, gx = x0 + 4*g - 4;
    float4 f = make_float4(0.f, 0.f, 0.f, 0.f);
    if ((unsigned)gy < 256u && (unsigned)gx < IWu) {
      if (FUSE == 0) {
        const float* xb = xp + (long)b_*786432 + (2*gy + 1)*512 + gx;
        float4 rr = *(const float4*)&xb[0];
        float4 gg = *(const float4*)&xb[262144];
        float4 bb = *(const float4*)&xb[524288];
        f.x = m0*rr.x + m1*gg.x + m2*bb.x;
        f.y = m0*rr.y + m1*gg.y + m2*bb.y;
        f.z = m0*rr.z + m1*gg.z + m2*bb.z;
        f.w = m0*rr.w + m1*gg.w + m2*bb.w;
      } else {
        const float* s = srcq + gy*512 + 2*gx;
        float4 a = *(const float4*)&s[0];
        float4 b = *(const float4*)&s[4];
        f = make_float4(a.y, a.w, b.y, b.w);        // odd cols
      }
    }
    __half2* d = (__half2*)&sOdd[ly*72 + 4*g];
    d[0] = __halves2half2(__float2half(f.x), __float2half(f.y));
    d[1] = __halves2half2(__float2half(f.z), __float2half(f.w));
  }
  __syncthreads();

  const __half2 zero2 = __builtin_bit_cast(__half2, 0u);
  const __half2 negb  = __halves2half2(__float2half(-60000.f), __float2half(-60000.f));
  const float b2p = bp2[0];

  // ---- phase A: predict-step on 68x68 region, 289 tiles, ONE pass ----
  if (tid < 289) {
    const int tyA = tid / 17, txA = tid - tyA*17;
    const int oyA = y0 - 2 + 4*tyA, oxA = x0 - 2 + 4*txA;
    __half2 E[8][4], O[8][3];
#pragma unroll
    for (int r = 0; r < 8; ++r) {
      const __half2* row = (const __half2*)&sEven[(4*tyA + r)*72 + 4*txA];
      E[r][0] = row[0]; E[r][1] = row[1]; E[r][2] = row[2]; E[r][3] = row[3];
      O[r][0] = oddpair(E[r][0], E[r][1]);
      O[r][1] = oddpair(E[r][1], E[r][2]);
      O[r][2] = oddpair(E[r][2], E[r][3]);
    }
    bool rowokA[6];
#pragma unroll
    for (int k = 0; k < 6; ++k) rowokA[k] = ((unsigned)(oyA - 1 + k) < 256u);
    const bool edgexT = (oxA <= 0) || (oxA >= IW - 4);
    __half2 mEA[3];
#pragma unroll
    for (int p = 0; p < 3; ++p) mEA[p] = zero2;
    if (edgexT) {
#pragma unroll
      for (int p = 0; p < 3; ++p) {
        float a = ((unsigned)(oxA - 1 + 2*p) < IWu) ? 1.f : 0.f;
        float b = ((unsigned)(oxA     + 2*p) < IWu) ? 1.f : 0.f;
        mEA[p] = __halves2half2(__float2half(a), __float2half(b));
      }
    }
    float   ACCF[4][4] = {{0,0,0,0},{0,0,0,0},{0,0,0,0},{0,0,0,0}};
    __half2 ACC2[4][2] = {{zero2,zero2},{zero2,zero2},{zero2,zero2},{zero2,zero2}};
#pragma unroll 1
    for (int c = 0; c < 16; ++c) {
      __half2 wv[20];
      load20(wv, &sWp[c*20]);
      channel_pass(wv, E, O, rowokA, edgexT, mEA, ACC2, negb);
      if ((c & 3) == 3) {
#pragma unroll
        for (int r = 0; r < 4; ++r)
#pragma unroll
          for (int cp = 0; cp < 2; ++cp) {
            ACCF[r][2*cp]   += __low2float(ACC2[r][cp]);
            ACCF[r][2*cp+1] += __high2float(ACC2[r][cp]);
            ACC2[r][cp] = zero2;
          }
      }
    }
    // epilogue: out = io - (acc + b2p), in-place over own io slots; OOB -> 0
#pragma unroll
    for (int r = 0; r < 4; ++r) {
      const int gy = oyA + r;
      const bool gyok = (unsigned)gy < 256u;
      __half2* iop = (__half2*)&sOdd[(4*tyA + r)*72 + 4*txA + 2];
      __half2 i01 = iop[0], i23 = iop[1];
      float o0 = __low2float (i01) - (ACCF[r][0] + b2p);
      float o1 = __high2float(i01) - (ACCF[r][1] + b2p);
      float o2 = __low2float (i23) - (ACCF[r][2] + b2p);
      float o3 = __high2float(i23) - (ACCF[r][3] + b2p);
      __half h0  = (gyok && (unsigned)(oxA+0) < IWu) ? __float2half(o0) : __half(0);
      __half h1  = (gyok && (unsigned)(oxA+1) < IWu) ? __float2half(o1) : __half(0);
      __half h2_ = (gyok && (unsigned)(oxA+2) < IWu) ? __float2half(o2) : __half(0);
      __half h3  = (gyok && (unsigned)(oxA+3) < IWu) ? __float2half(o3) : __half(0);
      iop[0] = __halves2half2(h0, h1);
      iop[1] = __halves2half2(h2_, h3);
    }
  }
  __syncthreads();

  // ---- interior f32 write of phase-A result + phase B (tid < 256) ----
  if (tid < 256) {
    const int tx = tid & 15, ty = tid >> 4;
    const int oy = y0 + 4*ty, ox = x0 + 4*tx;
    {
      float* pAdst = FUSE ? (outp + (long)(b_*12 + (which?9:3) + c_)*65536)
                          : (Hw + (long)n*131072);
#pragma unroll
      for (int r = 0; r < 4; ++r) {
        const __half2* q = (const __half2*)&sOdd[(4*ty + 2 + r)*72 + 4*tx + 4];
        __half2 a = q[0], b = q[1];
        float4 v = make_float4(__low2float(a), __high2float(a),
                               __low2float(b), __high2float(b));
        *(float4*)&pAdst[(oy + r)*IW + ox] = v;
      }
    }

    // phase B: update-step on interior 64x64
    __half2 E[8][4], O[8][3];
#pragma unroll
    for (int r = 0; r < 8; ++r) {
      const __half2* row = (const __half2*)&sOdd[(4*ty + r)*72 + 4*tx + 2];
      E[r][0] = row[0]; E[r][1] = row[1]; E[r][2] = row[2]; E[r][3] = row[3];
      O[r][0] = oddpair(E[r][0], E[r][1]);
      O[r][1] = oddpair(E[r][1], E[r][2]);
      O[r][2] = oddpair(E[r][2], E[r][3]);
    }
    bool rowok[6];
#pragma unroll
    for (int k = 0; k < 6; ++k) rowok[k] = ((unsigned)(oy - 1 + k) < 256u);
    const bool edgex = (x0 == 0) || (x0 + 64 == IW);
    __half2 mE[3];
#pragma unroll
    for (int p = 0; p < 3; ++p) mE[p] = zero2;
    if (edgex) {
#pragma unroll
      for (int p = 0; p < 3; ++p) {
        float a = ((unsigned)(ox - 1 + 2*p) < IWu) ? 1.f : 0.f;
        float b = ((unsigned)(ox     + 2*p) < IWu) ? 1.f : 0.f;
        mE[p] = __halves2half2(__float2half(a), __float2half(b));
      }
    }
    float   ACCF[4][4] = {{0,0,0,0},{0,0,0,0},{0,0,0,0},{0,0,0,0}};
    __half2 ACC2[4][2] = {{zero2,zero2},{zero2,zero2},{zero2,zero2},{zero2,zero2}};
#pragma unroll 1
    for (int c = 0; c < 16; ++c) {
      __half2 wv[20];
      load20(wv, &sWu[c*20]);
      channel_pass(wv, E, O, rowok, edgex, mE, ACC2, negb);
      if ((c & 3) == 3) {
#pragma unroll
        for (int r = 0; r < 4; ++r)
#pragma unroll
          for (int cp = 0; cp < 2; ++cp) {
            ACCF[r][2*cp]   += __low2float(ACC2[r][cp]);
            ACCF[r][2*cp+1] += __high2float(ACC2[r][cp]);
            ACC2[r][cp] = zero2;
          }
      }
    }
    // epilogue: out = io + (acc + b2u); io = sEven interior
    const float b2u = bu2[0];
    float* dst = FUSE ? (outp + (long)(b_*12 + (which?6:0) + c_)*65536)
                      : (Lw + (long)n*131072);
#pragma unroll
    for (int r = 0; r < 4; ++r) {
      const __half2* iop = (const __half2*)&sEven[(4*ty + 4 + r)*72 + 4*tx + 4];
      __half2 a = iop[0], b = iop[1];
      float4 v;
      v.x = __low2float (a) + (ACCF[r][0] + b2u);
      v.y = __high2float(a) + (ACCF[r][1] + b2u);
      v.z = __low2float (b) + (ACCF[r][2] + b2u);
      v.w = __high2float(b) + (ACCF[r][3] + b2u);
      *(float4*)&dst[(oy + r)*IW + ox] = v;
    }
  }
}

extern "C" void kernel_launch(void* const* d_in, const int* in_sizes, int n_in,
                              void* d_out, int out_size, void* d_ws, size_t ws_size,
                              hipStream_t stream) {
  const float* x   = (const float*)d_in[0];
  const float* Wp1 = (const float*)d_in[1];
  const float* bp1 = (const float*)d_in[2];
  const float* Wp2 = (const float*)d_in[3];
  const float* bp2 = (const float*)d_in[4];
  const float* Wu1 = (const float*)d_in[5];
  const float* bu1 = (const float*)d_in[6];
  const float* Wu2 = (const float*)d_in[7];
  const float* bu2 = (const float*)d_in[8];
  float* out = (float*)d_out;
  float* ws  = (float*)d_ws;

  // Launch A: stage-1 lift (rows): Hb' -> Hw, L' -> Lw
  k_pair<0><<<dim3(8,4,24), 512, 0, stream>>>(x, ws, out,
      Wp1, bp1, Wp2, bp2, Wu1, bu1, Wu2, bu2);
  // Launch B: stage-2 lift (cols, T wts): q1/q3 + q0/q2 -> out
  k_pair<1><<<dim3(4,4,48), 512, 0, stream>>>(x, ws, out,
      Wp1, bp1, Wp2, bp2, Wu1, bu1, Wu2, bu2);
}

// Round 13
// 241.385 us; speedup vs baseline: 1.8916x; 1.1269x over previous
//
#include <hip/hip_runtime.h>
#include <hip/hip_fp16.h>

// Wavelet lifting net, MI355X — 4 launches, packed-f16 math, 4x4 out/thread.
// SESSION KEEPER: byte-identical restore of the round-7 kernel (241.7us,
// best verified). Round-0 geometry (64x64 tile, 256 threads, 768 blocks,
// 3 blocks/CU) + two verified wins:
//  (1) MODE0 L side-write OUT of staging, written as aligned float4 from
//      E regs: WRITE_SIZE 28 -> 12.3 MB (kills scalar halo write-amp).
//  (2) staging loads vectorized: per row 16 aligned float4 groups + 4 edge
//      scalars; MODE2 stride-2 gather via 2x float4 + even extract.
// Retired paths (all measured worse):
//  - fusion via halo recompute: r8 252.5us (256t double-pass), r12 272us
//    (512t: FETCH 2x from L2-locality loss), r11 200us/launch
//    (launch_bounds(512,6) VGPR cap 85 -> scratch spill, VGPR 40, 208MB WRITE)
//  - coop launch / grid.sync: r2/r3 (graph-capture incompatible, silent fail)
//  - occupancy via smaller tiles: r1 (+33% redundancy, L2 thrash), r6 (null)
//  - epilogue io hoist: r4 (store-stream reorder -> +22% HBM bytes)
//  - weight ping-pong prefetch: r5 (null; ds lgkm latency is not the stall)
//  - 320-thread blocks: r9/r10 (container failures, banned)
// Diagnosis at plateau: latency/issue-bound single-generation lockstep
// (MODE2/3 run at 3% HBM and still ~50us; VALUBusy ~47%, occupancy
// grid-capped at 3 blocks/CU). Remaining lever (LDS-shared hidden map,
// ~2.25x conv1 redundancy) nets only ~3-5us/dispatch after barrier costs.
//  MODE0: in = YUV(x) even rows (on the fly); io = YUV odd; dst = Hb' (ws);
//         side-writes L (f32 from f16 regs, aligned).
//  MODE1: in = Hb' (halo); io = L; dst = L' (in-place in ws).
//  MODE2: in = even cols of L'/Hb'; io = odd cols; dst = d_out q1/q3. (T wts)
//  MODE3: in = d_out q1/q3; io = even cols; dst = d_out q0/q2.        (T wts)
// Hidden map is zero OUTSIDE the image (conv2 SAME pads hidden map):
// row-invalid folded into bias=-60000 (relu->0), col mask on edge blocks.
// conv2 accumulated f16 per 4-channel group, folded to fp32.

#define P1 (24*256*512)

__device__ __forceinline__ __half2 oddpair(__half2 a, __half2 b) {
  unsigned ua = __builtin_bit_cast(unsigned, a), ub = __builtin_bit_cast(unsigned, b);
  unsigned r = __builtin_amdgcn_alignbit(ub, ua, 16);
  return __builtin_bit_cast(__half2, r);
}

__device__ __forceinline__ __half2 relu2(__half2 s) {
  unsigned u = __builtin_bit_cast(unsigned, s), r;
  asm("v_pk_max_f16 %0, %1, 0" : "=v"(r) : "v"(u));
  return __builtin_bit_cast(__half2, r);
}

template<int MODE>
__global__ __launch_bounds__(256, 3) void k_subnet(
    const float* __restrict__ xp, float* __restrict__ ws, float* __restrict__ outp,
    const float* __restrict__ W1, const float* __restrict__ B1,
    const float* __restrict__ W2, const float* __restrict__ B2)
{
  constexpr int  IW    = (MODE <= 1) ? 512 : 256;
  constexpr int  HW    = 256 * IW;
  constexpr float sign = (MODE == 0 || MODE == 2) ? -1.f : 1.f;
  constexpr int  TRANS = (MODE >= 2) ? 1 : 0;

  __shared__ __align__(16) __half2 sW[16*20];   // per ch: w1[0..8], b1, w2[10..18], pad
  __shared__ __align__(16) __half  sIn[68*72];  // 64x64 tile + halo 2, stride 72

  const int z     = blockIdx.z;
  const int n     = (MODE >= 2) ? (z % 24) : z;
  const int which = (MODE >= 2) ? (z / 24) : 0;
  const int c_ = n >> 3, b_ = n & 7;
  const int x0 = blockIdx.x * 64, y0 = blockIdx.y * 64;
  const int tid = threadIdx.x;
  float* Lw = ws;
  float* Hw = ws + P1;

  // ---- weights -> LDS as broadcast half2 (transposed 3x3 if TRANS) ----
  for (int i = tid; i < 320; i += 256) {
    int cc = i / 20, j = i - cc*20;
    float v = 0.f;
    if (j < 9)       { int jt = TRANS ? ((j%3)*3 + j/3) : j; v = W1[cc*9 + jt]; }
    else if (j == 9) v = B1[cc];
    else if (j < 19) { int k = j - 10; int jt = TRANS ? ((k%3)*3 + k/3) : k; v = W2[cc*9 + jt]; }
    __half h = __float2half(v);
    sW[i] = __halves2half2(h, h);
  }

  // ---- input staging (68x68 halo-2 window), vectorized ----
  // Per row: 16 float4 groups (cols 2+4u <-> gx = x0+4u, always in-bounds in x)
  //          + 4 edge scalars (cols 0,1,66,67).
  float m0 = 0.f, m1 = 0.f, m2 = 0.f;
  if (MODE == 0) {
    m0 = (c_==0) ? 0.299f : ((c_==1) ? -0.147f :  0.615f);
    m1 = (c_==0) ? 0.587f : ((c_==1) ? -0.289f : -0.515f);
    m2 = (c_==0) ? 0.114f : ((c_==1) ?  0.436f : -0.100f);
  }
  for (int i = tid; i < 68*20; i += 256) {
    int ly = i / 20, u = i - ly*20;
    int gy = y0 + ly - 2;
    const bool rv = (unsigned)gy < 256u;
    if (u < 16) {
      int gx = x0 + 4*u;
      float4 f = make_float4(0.f, 0.f, 0.f, 0.f);
      if (rv) {
        if (MODE == 0) {
          const float* xb = xp + ((long)b_*3*512 + 2*gy)*512 + gx;
          float4 rr = *(const float4*)&xb[0];
          float4 gg = *(const float4*)&xb[262144];
          float4 bb = *(const float4*)&xb[524288];
          f.x = m0*rr.x + m1*gg.x + m2*bb.x;
          f.y = m0*rr.y + m1*gg.y + m2*bb.y;
          f.z = m0*rr.z + m1*gg.z + m2*bb.z;
          f.w = m0*rr.w + m1*gg.w + m2*bb.w;
        } else if (MODE == 1) {
          f = *(const float4*)&Hw[(long)n*HW + gy*IW + gx];
        } else if (MODE == 2) {
          const float* s = (which ? Hw : Lw) + (long)n*(256*512) + gy*512 + 2*gx;
          float4 a = *(const float4*)&s[0];
          float4 b = *(const float4*)&s[4];
          f = make_float4(a.x, a.z, b.x, b.z);             // even cols
        } else {
          const float* s = outp + (long)(b_*12 + (which?9:3) + c_)*65536;
          f = *(const float4*)&s[gy*256 + gx];
        }
      }
      __half* d = &sIn[ly*72 + 2 + 4*u];
      ((__half2*)d)[0] = __halves2half2(__float2half(f.x), __float2half(f.y));
      ((__half2*)d)[1] = __halves2half2(__float2half(f.z), __float2half(f.w));
    } else {
      int e = u - 16;
      int lx = (e < 2) ? e : (64 + e);                     // 0,1,66,67
      int gx = x0 + lx - 2;
      float v = 0.f;
      if (rv && (unsigned)gx < (unsigned)IW) {
        if (MODE == 0) {
          const float* xb = xp + ((long)b_*3*512 + 2*gy)*512 + gx;
          v = m0*xb[0] + m1*xb[262144] + m2*xb[524288];
        } else if (MODE == 1) {
          v = Hw[(long)n*HW + gy*IW + gx];
        } else if (MODE == 2) {
          const float* s = (which ? Hw : Lw) + (long)n*(256*512);
          v = s[gy*512 + 2*gx];
        } else {
          const float* s = outp + (long)(b_*12 + (which?9:3) + c_)*65536;
          v = s[gy*256 + gx];
        }
      }
      sIn[ly*72 + lx] = __float2half(v);
    }
  }
  __syncthreads();

  const int tx = tid & 15, ty = tid >> 4;        // 16 x 16 threads
  const int oy = y0 + ty*4, ox = x0 + tx*4;      // 4x4 outputs per thread

  // ---- 8x8 input window as half2 pairs, both alignments ----
  __half2 E[8][4], O[8][3];
#pragma unroll
  for (int r = 0; r < 8; ++r) {
    const __half2* row = (const __half2*)&sIn[(ty*4 + r)*72 + tx*4];
    E[r][0] = row[0]; E[r][1] = row[1]; E[r][2] = row[2]; E[r][3] = row[3];
    O[r][0] = oddpair(E[r][0], E[r][1]);
    O[r][1] = oddpair(E[r][1], E[r][2]);
    O[r][2] = oddpair(E[r][2], E[r][3]);
  }

  // ---- MODE0: aligned L side-write from E regs (full 64B lines) ----
  // E[r+2][1],E[r+2][2] = sIn cols tx*4+2..tx*4+5 = gx ox..ox+3, row oy+r.
  if (MODE == 0) {
    float* Ld = Lw + (long)n*HW;
#pragma unroll
    for (int r = 0; r < 4; ++r) {
      float4 v;
      v.x = __low2float (E[r+2][1]);
      v.y = __high2float(E[r+2][1]);
      v.z = __low2float (E[r+2][2]);
      v.w = __high2float(E[r+2][2]);
      *(float4*)&Ld[(oy + r)*IW + ox] = v;
    }
  }

  // ---- hidden-map validity ----
  const bool edgex = (x0 == 0) || (x0 + 64 == IW);
  bool rowok[6];
#pragma unroll
  for (int k = 0; k < 6; ++k) rowok[k] = ((unsigned)(oy - 1 + k) < 256u);
  __half2 mE[3];
  if (edgex) {
#pragma unroll
    for (int p = 0; p < 3; ++p) {
      float a = ((unsigned)(ox - 1 + 2*p) < (unsigned)IW) ? 1.f : 0.f;
      float b = ((unsigned)(ox     + 2*p) < (unsigned)IW) ? 1.f : 0.f;
      mE[p] = __halves2half2(__float2half(a), __float2half(b));
    }
  }

  const __half2 zero2 = __builtin_bit_cast(__half2, 0u);
  const __half2 negb  = __halves2half2(__float2half(-60000.f), __float2half(-60000.f));

  float   ACCF[4][4] = {{0,0,0,0},{0,0,0,0},{0,0,0,0},{0,0,0,0}};
  __half2 ACC2[4][2] = {{zero2,zero2},{zero2,zero2},{zero2,zero2},{zero2,zero2}};

#pragma unroll 1
  for (int c = 0; c < 16; ++c) {
    __half2 wv[20];
    const float4* wq = (const float4*)&sW[c*20];
#pragma unroll
    for (int q = 0; q < 5; ++q) {
      float4 f = wq[q];
      wv[4*q+0] = __builtin_bit_cast(__half2, f.x);
      wv[4*q+1] = __builtin_bit_cast(__half2, f.y);
      wv[4*q+2] = __builtin_bit_cast(__half2, f.z);
      wv[4*q+3] = __builtin_bit_cast(__half2, f.w);
    }
    __half2 bias[6];
#pragma unroll
    for (int k = 0; k < 6; ++k) bias[k] = rowok[k] ? wv[9] : negb;

#pragma unroll
    for (int kk = 0; kk < 6; ++kk) {
      __half2 HE[3];
#pragma unroll
      for (int p = 0; p < 3; ++p) {
        __half2 hs = bias[kk];
#pragma unroll
        for (int dy = 0; dy < 3; ++dy) {
          hs = __hfma2(wv[dy*3+0], E[kk+dy][p],   hs);
          hs = __hfma2(wv[dy*3+1], O[kk+dy][p],   hs);
          hs = __hfma2(wv[dy*3+2], E[kk+dy][p+1], hs);
        }
        HE[p] = relu2(hs);
      }
      if (edgex) {
        HE[0] = __hmul2(HE[0], mE[0]);
        HE[1] = __hmul2(HE[1], mE[1]);
        HE[2] = __hmul2(HE[2], mE[2]);
      }
      __half2 HO0 = oddpair(HE[0], HE[1]);
      __half2 HO1 = oddpair(HE[1], HE[2]);
#pragma unroll
      for (int dy = 0; dy < 3; ++dy) {
        const int r = kk - dy;
        if (r >= 0 && r < 4) {
#pragma unroll
          for (int cp = 0; cp < 2; ++cp) {
            __half2 a = ACC2[r][cp];
            a = __hfma2(wv[10+dy*3+0], HE[cp],           a);
            a = __hfma2(wv[10+dy*3+1], (cp ? HO1 : HO0), a);
            a = __hfma2(wv[10+dy*3+2], HE[cp+1],         a);
            ACC2[r][cp] = a;
          }
        }
      }
    }
    if ((c & 3) == 3) {      // fold f16 group accumulator into fp32
#pragma unroll
      for (int r = 0; r < 4; ++r)
#pragma unroll
        for (int cp = 0; cp < 2; ++cp) {
          ACCF[r][2*cp]   += __low2float(ACC2[r][cp]);
          ACCF[r][2*cp+1] += __high2float(ACC2[r][cp]);
          ACC2[r][cp] = zero2;
        }
    }
  }

  // ---- epilogue: out = io + sign*(acc + b2) ----
  const float b2 = B2[0];
  float4 iov[4];
  if (MODE == 0) {
#pragma unroll
    for (int r = 0; r < 4; ++r) {
      const float* xb = xp + ((long)b_*3*512 + (2*(oy+r)+1))*512 + ox;
      float4 rr = *(const float4*)&xb[0];
      float4 gg = *(const float4*)&xb[262144];
      float4 bb = *(const float4*)&xb[524288];
      iov[r] = make_float4(m0*rr.x + m1*gg.x + m2*bb.x,
                           m0*rr.y + m1*gg.y + m2*bb.y,
                           m0*rr.z + m1*gg.z + m2*bb.z,
                           m0*rr.w + m1*gg.w + m2*bb.w);
    }
  } else if (MODE == 1) {
    const float* s = Lw + (long)n*HW;
#pragma unroll
    for (int r = 0; r < 4; ++r) iov[r] = *(const float4*)&s[(oy+r)*IW + ox];
  } else {
    const float* s = (which ? Hw : Lw) + (long)n*(256*512);
#pragma unroll
    for (int r = 0; r < 4; ++r) {
      float4 a = *(const float4*)&s[(oy+r)*512 + 2*ox];
      float4 b = *(const float4*)&s[(oy+r)*512 + 2*ox + 4];
      iov[r] = (MODE == 2) ? make_float4(a.y, a.w, b.y, b.w)    // odd cols
                           : make_float4(a.x, a.z, b.x, b.z);   // even cols
    }
  }

  float* dst;
  if      (MODE == 0) dst = Hw + (long)n*HW;
  else if (MODE == 1) dst = Lw + (long)n*HW;
  else if (MODE == 2) dst = outp + (long)(b_*12 + (which?9:3) + c_)*65536;
  else                dst = outp + (long)(b_*12 + (which?6:0) + c_)*65536;

#pragma unroll
  for (int r = 0; r < 4; ++r) {
    float4 v;
    v.x = iov[r].x + sign * (ACCF[r][0] + b2);
    v.y = iov[r].y + sign * (ACCF[r][1] + b2);
    v.z = iov[r].z + sign * (ACCF[r][2] + b2);
    v.w = iov[r].w + sign * (ACCF[r][3] + b2);
    *(float4*)&dst[(oy + r)*IW + ox] = v;
  }
}

extern "C" void kernel_launch(void* const* d_in, const int* in_sizes, int n_in,
                              void* d_out, int out_size, void* d_ws, size_t ws_size,
                              hipStream_t stream) {
  const float* x   = (const float*)d_in[0];
  const float* Wp1 = (const float*)d_in[1];
  const float* bp1 = (const float*)d_in[2];
  const float* Wp2 = (const float*)d_in[3];
  const float* bp2 = (const float*)d_in[4];
  const float* Wu1 = (const float*)d_in[5];
  const float* bu1 = (const float*)d_in[6];
  const float* Wu2 = (const float*)d_in[7];
  const float* bu2 = (const float*)d_in[8];
  float* out = (float*)d_out;
  float* ws  = (float*)d_ws;

  // S1P: Hb' = Hb - p(L); materializes L
  k_subnet<0><<<dim3(8,4,24), 256, 0, stream>>>(x, ws, out, Wp1, bp1, Wp2, bp2);
  // S1U: L' = L + u(Hb')
  k_subnet<1><<<dim3(8,4,24), 256, 0, stream>>>(x, ws, out, Wu1, bu1, Wu2, bu2);
  // S2P: HL' = HL - pT(LL) -> q1 ; HH' = HH - pT(LH) -> q3
  k_subnet<2><<<dim3(4,4,48), 256, 0, stream>>>(x, ws, out, Wp1, bp1, Wp2, bp2);
  // S2U: LL' = LL + uT(HL') -> q0 ; LH' = LH + uT(HH') -> q2
  k_subnet<3><<<dim3(4,4,48), 256, 0, stream>>>(x, ws, out, Wu1, bu1, Wu2, bu2);
}